// Round 6
// baseline (291.146 us; speedup 1.0000x reference)
//
#include <hip/hip_runtime.h>
#include <hip/hip_bf16.h>
#include <math.h>
#include <stdint.h>

#define DIM   64
#define KNB   16
#define QKVW  192
#define H2PAD 272   // fused-fallback layout
#define KVPAD 144

typedef short bf16x8 __attribute__((ext_vector_type(8)));
typedef float f32x4  __attribute__((ext_vector_type(4)));

__device__ __forceinline__ short f2bf_s(float x) {
    return (short)__builtin_bit_cast(unsigned short, __float2bfloat16(x));
}
__device__ __forceinline__ float bf2f(uint16_t u) {
    uint32_t v = ((uint32_t)u) << 16;
    return __builtin_bit_cast(float, v);
}

// ---------------------------------------------------------------------------
// qkv: 16 rows per block, x staged in LDS. q -> f32 [N][64]; k,v -> bf16 [N][128].
// ---------------------------------------------------------------------------
__global__ __launch_bounds__(256) void qkv_kernel(
    const float* __restrict__ x, const float* __restrict__ wqkv,
    float* __restrict__ qf, uint16_t* __restrict__ kvp, int n)
{
    const int tid = threadIdx.x;
    const int c   = tid & 63;
    const int rq  = tid >> 6;
    const int r0  = blockIdx.x * 16;
    __shared__ float s_x[16][64];
#pragma unroll
    for (int t = 0; t < 4; ++t) {
        const int row = r0 + rq + 4 * t;
        s_x[rq + 4 * t][c] = (row < n) ? x[(size_t)row * 64 + c] : 0.f;
    }
    __syncthreads();
    float aq[4] = {0, 0, 0, 0}, ak[4] = {0, 0, 0, 0}, av[4] = {0, 0, 0, 0};
    for (int d = 0; d < 64; ++d) {
        const float w0 = wqkv[d * QKVW + c];
        const float w1 = wqkv[d * QKVW + 64 + c];
        const float w2 = wqkv[d * QKVW + 128 + c];
#pragma unroll
        for (int t = 0; t < 4; ++t) {
            const float xv = s_x[rq + 4 * t][d];
            aq[t] = fmaf(xv, w0, aq[t]);
            ak[t] = fmaf(xv, w1, ak[t]);
            av[t] = fmaf(xv, w2, av[t]);
        }
    }
#pragma unroll
    for (int t = 0; t < 4; ++t) {
        const int row = r0 + rq + 4 * t;
        if (row < n) {
            qf[(size_t)row * 64 + c]        = aq[t];
            kvp[(size_t)row * 128 + c]      = (uint16_t)f2bf_s(ak[t]);
            kvp[(size_t)row * 128 + 64 + c] = (uint16_t)f2bf_s(av[t]);
        }
    }
}

// ---------------------------------------------------------------------------
// Prepack am_w1 / am_w2 / pm_w2 into bf16 MFMA fragment order.
// Fragment: non-K = lane&15, K = 32*kt + 8*(lane>>4) + j.
// ---------------------------------------------------------------------------
__global__ __launch_bounds__(256) void wpack_kernel(
    const float* __restrict__ am_w1, const float* __restrict__ am_w2,
    const float* __restrict__ pm_w2,
    uint16_t* __restrict__ w1p, uint16_t* __restrict__ w2p, uint16_t* __restrict__ pw2p)
{
    int t = blockIdx.x * 256 + threadIdx.x;
    if (t >= 36864) return;
    int j = t & 7, lane = (t >> 3) & 63, tile = t >> 9;
    int g = lane >> 4, nb = lane & 15;
    if (tile < 32) {
        int mt = tile >> 1, kt = tile & 1;
        w1p[t] = (uint16_t)f2bf_s(am_w1[(32 * kt + 8 * g + j) * 256 + 16 * mt + nb]);
    } else if (tile < 64) {
        int tt = tile - 32;
        int mt = tt >> 3, kt = tt & 7;
        w2p[t - 16384] = (uint16_t)f2bf_s(am_w2[(32 * kt + 8 * g + j) * 64 + 16 * mt + nb]);
    } else {
        int tt = tile - 64;
        int nt = tt >> 1, kt = tt & 1;
        pw2p[t - 32768] = (uint16_t)f2bf_s(pm_w2[(32 * kt + 8 * g + j) * 64 + 16 * nt + nb]);
    }
}

// ---------------------------------------------------------------------------
// posmlp: rel'[p][c] = relu(rp[p] @ pm_w1 + b1) @ pm_w2 + b2 - q[i(p)][c], bf16.
// Block = 64 pairs (4 points). Wave w owns pairs 16w..16w+15 (MFMA M-tile).
// relp is slab-local: row = p_global - slab_start*16.
// ---------------------------------------------------------------------------
__global__ __launch_bounds__(256) void posmlp_kernel(
    const float* __restrict__ pos, const int* __restrict__ aidx,
    const float* __restrict__ pm_w1, const float* __restrict__ pm_b1,
    const float* __restrict__ pm_b2, const float* __restrict__ qf,
    const uint16_t* __restrict__ pw2p, uint16_t* __restrict__ relp,
    int slab_start, int n)
{
    const int tid  = threadIdx.x;
    const int w    = tid >> 6;
    const int lane = tid & 63;
    const int g    = (lane >> 4) & 3;
    const int nb   = lane & 15;
    const int p0   = slab_start * KNB + blockIdx.x * 64;   // global pair base
    const int ptotal = n * KNB;

    __shared__ float s_rp[64][4];
    __shared__ float s_q[4][64];

    if (tid < 192) {
        const int pl = tid / 3, a = tid - 3 * pl;
        const int p = p0 + pl;
        float v = 0.f;
        if (p < ptotal) {
            const int i = p >> 4;
            v = pos[3 * aidx[p] + a] - pos[3 * i + a];
        }
        s_rp[pl][a] = v;
    }
    {
        const int i = (p0 >> 4) + (tid >> 6);
        s_q[tid >> 6][tid & 63] = (i < n) ? qf[(size_t)i * 64 + (tid & 63)] : 0.f;
    }
    __syncthreads();

    const int pl = 16 * w + nb;
    const float rx = s_rp[pl][0], ry = s_rp[pl][1], rz = s_rp[pl][2];

    bf16x8 h1f[2];
#pragma unroll
    for (int kt = 0; kt < 2; ++kt) {
        const int hb = 32 * kt + 8 * g;
        float w0[8], w1r[8], w2r[8], bb[8];
        *(float4*)&w0[0]  = *(const float4*)(pm_w1 + hb);
        *(float4*)&w0[4]  = *(const float4*)(pm_w1 + hb + 4);
        *(float4*)&w1r[0] = *(const float4*)(pm_w1 + 64 + hb);
        *(float4*)&w1r[4] = *(const float4*)(pm_w1 + 64 + hb + 4);
        *(float4*)&w2r[0] = *(const float4*)(pm_w1 + 128 + hb);
        *(float4*)&w2r[4] = *(const float4*)(pm_w1 + 128 + hb + 4);
        *(float4*)&bb[0]  = *(const float4*)(pm_b1 + hb);
        *(float4*)&bb[4]  = *(const float4*)(pm_b1 + hb + 4);
        bf16x8 f;
#pragma unroll
        for (int jj = 0; jj < 8; ++jj) {
            float v = fmaf(rx, w0[jj], fmaf(ry, w1r[jj], fmaf(rz, w2r[jj], bb[jj])));
            f[jj] = f2bf_s(fmaxf(v, 0.f));
        }
        h1f[kt] = f;
    }

#pragma unroll
    for (int nt = 0; nt < 4; ++nt) {
        const bf16x8 b0 = *(const bf16x8*)(pw2p + (size_t)((nt * 2 + 0) * 64 + lane) * 8);
        const bf16x8 b1 = *(const bf16x8*)(pw2p + (size_t)((nt * 2 + 1) * 64 + lane) * 8);
        f32x4 acc = {0.f, 0.f, 0.f, 0.f};
        acc = __builtin_amdgcn_mfma_f32_16x16x32_bf16(h1f[0], b0, acc, 0, 0, 0);
        acc = __builtin_amdgcn_mfma_f32_16x16x32_bf16(h1f[1], b1, acc, 0, 0, 0);
        const int ch = 16 * nt + nb;
        const float bias = pm_b2[ch];
#pragma unroll
        for (int r = 0; r < 4; ++r) {
            const int plr = 16 * w + 4 * g + r;
            const int p = p0 + plr;
            if (p < ptotal) {
                const float val = acc[r] + bias - s_q[plr >> 4][ch];
                relp[(size_t)(blockIdx.x * 64 + plr) * 64 + ch] = (uint16_t)f2bf_s(val);
            }
        }
    }
}

// ---------------------------------------------------------------------------
// Main (precomputed-rel path). One barrier/point (h2 transpose, dbuf'd).
// s_h2 XOR-swizzle: byte = nb*512 + (2*h ^ 64*(nb&7)); scores reads conflict-free.
// t = k + rel' from global (L2/L3); agg uses v/rel' as 4-row 32B gathers.
// ---------------------------------------------------------------------------
__global__ __launch_bounds__(256, 2) void ptl_main(
    const int* __restrict__ aidx,
    const uint8_t* __restrict__ mask,
    const float* __restrict__ qf,
    const uint16_t* __restrict__ kvp,
    const uint16_t* __restrict__ relp,
    const uint16_t* __restrict__ w1p,
    const uint16_t* __restrict__ w2p,
    const float* __restrict__ am_b1,
    float* __restrict__ out,
    int slab_start, int slab_end)
{
    const int tid  = threadIdx.x;
    const int w    = tid >> 6;
    const int lane = tid & 63;
    const int g    = (lane >> 4) & 3;
    const int nb   = lane & 15;
    const int swz  = 64 * (nb & 7);

    __shared__ alignas(16) uint16_t s_h2[2][16 * 256];

    bf16x8 aw1[4][2], aw2[8];
#pragma unroll
    for (int m = 0; m < 4; ++m)
#pragma unroll
        for (int kt = 0; kt < 2; ++kt)
            aw1[m][kt] = *(const bf16x8*)(w1p + (size_t)(((4 * w + m) * 2 + kt) * 64 + lane) * 8);
#pragma unroll
    for (int kt = 0; kt < 8; ++kt)
        aw2[kt] = *(const bf16x8*)(w2p + (size_t)((w * 8 + kt) * 64 + lane) * 8);

    int buf = 0;
    for (int i = slab_start + blockIdx.x; i < slab_end; i += gridDim.x, buf ^= 1) {
        const int nidx = aidx[i * KNB + nb];
        const size_t lrow = (size_t)((i - slab_start) * KNB);

        // ---- t = k + rel' -> B-frags ----
        bf16x8 tf[2];
#pragma unroll
        for (int kt = 0; kt < 2; ++kt) {
            const bf16x8 k8 = *(const bf16x8*)(kvp + (size_t)nidx * 128 + 32 * kt + 8 * g);
            const bf16x8 r8 = *(const bf16x8*)(relp + (lrow + nb) * 64 + 32 * kt + 8 * g);
            bf16x8 f;
#pragma unroll
            for (int jj = 0; jj < 8; ++jj)
                f[jj] = f2bf_s(bf2f((uint16_t)k8[jj]) + bf2f((uint16_t)r8[jj]));
            tf[kt] = f;
        }

        // ---- h2 slices (wave w: hidden 64w..64w+63) ----
        f32x4 hacc[4];
#pragma unroll
        for (int m = 0; m < 4; ++m) {
            f32x4 a = {0.f, 0.f, 0.f, 0.f};
            a = __builtin_amdgcn_mfma_f32_16x16x32_bf16(aw1[m][0], tf[0], a, 0, 0, 0);
            a = __builtin_amdgcn_mfma_f32_16x16x32_bf16(aw1[m][1], tf[1], a, 0, 0, 0);
            hacc[m] = a;
        }
#pragma unroll
        for (int m = 0; m < 4; ++m) {
            const int hb = 16 * (4 * w + m) + 4 * g;
            const float4 b4 = *(const float4*)(am_b1 + hb);
            const uint32_t lo = (uint32_t)(uint16_t)f2bf_s(fmaxf(hacc[m][0] + b4.x, 0.f))
                              | ((uint32_t)(uint16_t)f2bf_s(fmaxf(hacc[m][1] + b4.y, 0.f)) << 16);
            const uint32_t hi = (uint32_t)(uint16_t)f2bf_s(fmaxf(hacc[m][2] + b4.z, 0.f))
                              | ((uint32_t)(uint16_t)f2bf_s(fmaxf(hacc[m][3] + b4.w, 0.f)) << 16);
            *(uint2*)((char*)&s_h2[buf][0] + nb * 512 + ((2 * hb) ^ swz)) = make_uint2(lo, hi);
        }
        __syncthreads();

        // ---- scores: D[nb][16w+nb'] = h2 @ w2 ----
        f32x4 wacc = {0.f, 0.f, 0.f, 0.f};
#pragma unroll
        for (int kt = 0; kt < 8; ++kt) {
            const bf16x8 bh2 = *(const bf16x8*)((const char*)&s_h2[buf][0] + nb * 512 + ((64 * kt + 16 * g) ^ swz));
            wacc = __builtin_amdgcn_mfma_f32_16x16x32_bf16(bh2, aw2[kt], wacc, 0, 0, 0);
        }

        // ---- softmax over neighbors (rows 4g+r per lane) ----
        const uchar4 m4 = *(const uchar4*)(mask + (size_t)i * KNB + 4 * g);
        const float sc0 = m4.x ? -INFINITY : wacc[0];
        const float sc1 = m4.y ? -INFINITY : wacc[1];
        const float sc2 = m4.z ? -INFINITY : wacc[2];
        const float sc3 = m4.w ? -INFINITY : wacc[3];
        float mx = fmaxf(fmaxf(sc0, sc1), fmaxf(sc2, sc3));
        mx = fmaxf(mx, __shfl_xor(mx, 16));
        mx = fmaxf(mx, __shfl_xor(mx, 32));
        const float e0 = __expf(sc0 - mx), e1 = __expf(sc1 - mx);
        const float e2 = __expf(sc2 - mx), e3 = __expf(sc3 - mx);
        float den = (e0 + e1) + (e2 + e3);

        // ---- num = sum_r e_r * (v_r + rel'_r + q_c) ----
        const float qc = qf[(size_t)i * 64 + 16 * w + nb];
        const int vcol = 64 + 16 * w + nb;
        const int rcol = 16 * w + nb;
        const int r0i = __shfl(nidx, 4 * g + 0);
        const int r1i = __shfl(nidx, 4 * g + 1);
        const int r2i = __shfl(nidx, 4 * g + 2);
        const int r3i = __shfl(nidx, 4 * g + 3);
        float num;
        {
            const float v0 = bf2f(kvp[(size_t)r0i * 128 + vcol]);
            const float v1 = bf2f(kvp[(size_t)r1i * 128 + vcol]);
            const float v2 = bf2f(kvp[(size_t)r2i * 128 + vcol]);
            const float v3 = bf2f(kvp[(size_t)r3i * 128 + vcol]);
            const float rr0 = bf2f(relp[(lrow + 4 * g + 0) * 64 + rcol]);
            const float rr1 = bf2f(relp[(lrow + 4 * g + 1) * 64 + rcol]);
            const float rr2 = bf2f(relp[(lrow + 4 * g + 2) * 64 + rcol]);
            const float rr3 = bf2f(relp[(lrow + 4 * g + 3) * 64 + rcol]);
            num = e0 * (v0 + rr0 + qc);
            num = fmaf(e1, v1 + rr1 + qc, num);
            num = fmaf(e2, v2 + rr2 + qc, num);
            num = fmaf(e3, v3 + rr3 + qc, num);
        }
        den += __shfl_xor(den, 16); den += __shfl_xor(den, 32);
        num += __shfl_xor(num, 16); num += __shfl_xor(num, 32);
        if (lane < 16)
            out[(size_t)i * 64 + 16 * w + nb] = __fdividef(num, den);
    }
}

// ---------------------------------------------------------------------------
// Fused fallback (round-5 kernel, proven): used when workspace is too small.
// ---------------------------------------------------------------------------
__global__ __launch_bounds__(256, 2) void ptl_main_fused(
    const float* __restrict__ pos,
    const int* __restrict__ aidx,
    const uint8_t* __restrict__ mask,
    const float* __restrict__ pm_w1,
    const float* __restrict__ pm_b1,
    const float* __restrict__ pm_b2,
    const float* __restrict__ am_b1,
    const float* __restrict__ qf,
    const uint16_t* __restrict__ kvp,
    const uint16_t* __restrict__ w1p,
    const uint16_t* __restrict__ w2p,
    const uint16_t* __restrict__ pw2p,
    float* __restrict__ out,
    int npts)
{
    const int tid  = threadIdx.x;
    const int w    = tid >> 6;
    const int lane = tid & 63;
    const int g    = lane >> 4;
    const int nb   = lane & 15;
    const int swz_nb = 16 * (nb & 7);

    __shared__ alignas(16) float    s_rel[2][1024];
    __shared__ alignas(16) uint16_t s_h2[2][16 * H2PAD];
    __shared__ alignas(16) uint16_t s_kv[2][16 * KVPAD];

    bf16x8 aw1[4][2], aw2[8], bpw2[2];
#pragma unroll
    for (int m = 0; m < 4; ++m)
#pragma unroll
        for (int kt = 0; kt < 2; ++kt)
            aw1[m][kt] = *(const bf16x8*)(w1p + (size_t)(((4 * w + m) * 2 + kt) * 64 + lane) * 8);
#pragma unroll
    for (int kt = 0; kt < 8; ++kt)
        aw2[kt] = *(const bf16x8*)(w2p + (size_t)((w * 8 + kt) * 64 + lane) * 8);
#pragma unroll
    for (int kt = 0; kt < 2; ++kt)
        bpw2[kt] = *(const bf16x8*)(pw2p + (size_t)((w * 2 + kt) * 64 + lane) * 8);

    const int srow = tid >> 4, schunk = tid & 15;
    const int relw_byte0 = 4 * (16 * w + nb);

    int buf = 0;
    for (int i = blockIdx.x; i < npts; i += gridDim.x, buf ^= 1) {
        {
            const int sidx = aidx[i * KNB + srow];
            const uint4 d4 = *(const uint4*)(kvp + (size_t)sidx * 128 + schunk * 8);
            *(uint4*)&s_kv[buf][srow * KVPAD + schunk * 8] = d4;
        }
        const int nidx = aidx[i * KNB + nb];
        const float rx = pos[3 * nidx]     - pos[3 * i];
        const float ry = pos[3 * nidx + 1] - pos[3 * i + 1];
        const float rz = pos[3 * nidx + 2] - pos[3 * i + 2];

        bf16x8 h1f[2];
#pragma unroll
        for (int kt = 0; kt < 2; ++kt) {
            const int hb = 32 * kt + 8 * g;
            float w0[8], w1r[8], w2r[8], bb[8];
            *(float4*)&w0[0]  = *(const float4*)(pm_w1 + hb);
            *(float4*)&w0[4]  = *(const float4*)(pm_w1 + hb + 4);
            *(float4*)&w1r[0] = *(const float4*)(pm_w1 + 64 + hb);
            *(float4*)&w1r[4] = *(const float4*)(pm_w1 + 64 + hb + 4);
            *(float4*)&w2r[0] = *(const float4*)(pm_w1 + 128 + hb);
            *(float4*)&w2r[4] = *(const float4*)(pm_w1 + 128 + hb + 4);
            *(float4*)&bb[0]  = *(const float4*)(pm_b1 + hb);
            *(float4*)&bb[4]  = *(const float4*)(pm_b1 + hb + 4);
            bf16x8 f;
#pragma unroll
            for (int jj = 0; jj < 8; ++jj) {
                float v = fmaf(rx, w0[jj], fmaf(ry, w1r[jj], fmaf(rz, w2r[jj], bb[jj])));
                f[jj] = f2bf_s(fmaxf(v, 0.f));
            }
            h1f[kt] = f;
        }

        f32x4 racc = {0.f, 0.f, 0.f, 0.f};
        racc = __builtin_amdgcn_mfma_f32_16x16x32_bf16(h1f[0], bpw2[0], racc, 0, 0, 0);
        racc = __builtin_amdgcn_mfma_f32_16x16x32_bf16(h1f[1], bpw2[1], racc, 0, 0, 0);
        const float pb2 = pm_b2[16 * w + nb];
        const float qc  = qf[(size_t)i * 64 + 16 * w + nb];
        f32x4 relagg;
#pragma unroll
        for (int r = 0; r < 4; ++r) {
            relagg[r] = racc[r] + pb2;
            const int row = 4 * g + r;
            *(float*)((char*)&s_rel[buf][0] + row * 256 + (relw_byte0 ^ (16 * (row & 7)))) =
                relagg[r] - qc;
        }
        __syncthreads();

        bf16x8 tf[2];
#pragma unroll
        for (int kt = 0; kt < 2; ++kt) {
            const bf16x8 k8 = *(const bf16x8*)&s_kv[buf][nb * KVPAD + 32 * kt + 8 * g];
            const float4 rl0 = *(const float4*)((const char*)&s_rel[buf][0] + nb * 256 + ((128 * kt + 32 * g) ^ swz_nb));
            const float4 rl1 = *(const float4*)((const char*)&s_rel[buf][0] + nb * 256 + ((128 * kt + 32 * g + 16) ^ swz_nb));
            const float rv[8] = {rl0.x, rl0.y, rl0.z, rl0.w, rl1.x, rl1.y, rl1.z, rl1.w};
            bf16x8 f;
#pragma unroll
            for (int jj = 0; jj < 8; ++jj)
                f[jj] = f2bf_s(bf2f((uint16_t)k8[jj]) + rv[jj]);
            tf[kt] = f;
        }

        f32x4 hacc[4];
#pragma unroll
        for (int m = 0; m < 4; ++m) {
            f32x4 a = {0.f, 0.f, 0.f, 0.f};
            a = __builtin_amdgcn_mfma_f32_16x16x32_bf16(aw1[m][0], tf[0], a, 0, 0, 0);
            a = __builtin_amdgcn_mfma_f32_16x16x32_bf16(aw1[m][1], tf[1], a, 0, 0, 0);
            hacc[m] = a;
        }
#pragma unroll
        for (int m = 0; m < 4; ++m) {
            const int hb = 16 * (4 * w + m) + 4 * g;
            const float4 b4 = *(const float4*)(am_b1 + hb);
            const uint32_t lo = (uint32_t)(uint16_t)f2bf_s(fmaxf(hacc[m][0] + b4.x, 0.f))
                              | ((uint32_t)(uint16_t)f2bf_s(fmaxf(hacc[m][1] + b4.y, 0.f)) << 16);
            const uint32_t hi = (uint32_t)(uint16_t)f2bf_s(fmaxf(hacc[m][2] + b4.z, 0.f))
                              | ((uint32_t)(uint16_t)f2bf_s(fmaxf(hacc[m][3] + b4.w, 0.f)) << 16);
            *(uint2*)&s_h2[buf][nb * H2PAD + hb] = make_uint2(lo, hi);
        }
        __syncthreads();

        f32x4 wacc = {0.f, 0.f, 0.f, 0.f};
#pragma unroll
        for (int kt = 0; kt < 8; ++kt) {
            const bf16x8 bh2 = *(const bf16x8*)&s_h2[buf][nb * H2PAD + 32 * kt + 8 * g];
            wacc = __builtin_amdgcn_mfma_f32_16x16x32_bf16(bh2, aw2[kt], wacc, 0, 0, 0);
        }

        const uchar4 m4 = *(const uchar4*)(mask + (size_t)i * KNB + 4 * g);
        float sc0 = m4.x ? -INFINITY : wacc[0];
        float sc1 = m4.y ? -INFINITY : wacc[1];
        float sc2 = m4.z ? -INFINITY : wacc[2];
        float sc3 = m4.w ? -INFINITY : wacc[3];
        float mx = fmaxf(fmaxf(sc0, sc1), fmaxf(sc2, sc3));
        mx = fmaxf(mx, __shfl_xor(mx, 16));
        mx = fmaxf(mx, __shfl_xor(mx, 32));
        const float e0 = __expf(sc0 - mx), e1 = __expf(sc1 - mx);
        const float e2 = __expf(sc2 - mx), e3 = __expf(sc3 - mx);
        float den = (e0 + e1) + (e2 + e3);

        const int vcol = 64 + 16 * w + nb;
        float num;
        {
            const float v0 = bf2f(s_kv[buf][(4 * g + 0) * KVPAD + vcol]);
            const float v1 = bf2f(s_kv[buf][(4 * g + 1) * KVPAD + vcol]);
            const float v2 = bf2f(s_kv[buf][(4 * g + 2) * KVPAD + vcol]);
            const float v3 = bf2f(s_kv[buf][(4 * g + 3) * KVPAD + vcol]);
            num = e0 * (v0 + relagg[0]);
            num = fmaf(e1, v1 + relagg[1], num);
            num = fmaf(e2, v2 + relagg[2], num);
            num = fmaf(e3, v3 + relagg[3], num);
        }
        den += __shfl_xor(den, 16); den += __shfl_xor(den, 32);
        num += __shfl_xor(num, 16); num += __shfl_xor(num, 32);
        if (lane < 16)
            out[(size_t)i * 64 + 16 * w + nb] = __fdividef(num, den);
    }
}

// ---------------------------------------------------------------------------
extern "C" void kernel_launch(void* const* d_in, const int* in_sizes, int n_in,
                              void* d_out, int out_size, void* d_ws, size_t ws_size,
                              hipStream_t stream) {
    const float*   x     = (const float*)d_in[0];
    const float*   pos   = (const float*)d_in[1];
    const int*     aidx  = (const int*)d_in[2];
    const uint8_t* mask  = (const uint8_t*)d_in[3];
    const float*   wqkv  = (const float*)d_in[4];
    const float*   pm_w1 = (const float*)d_in[5];
    const float*   pm_b1 = (const float*)d_in[6];
    const float*   pm_w2 = (const float*)d_in[7];
    const float*   pm_b2 = (const float*)d_in[8];
    const float*   am_w1 = (const float*)d_in[9];
    const float*   am_b1 = (const float*)d_in[10];
    const float*   am_w2 = (const float*)d_in[11];
    // am_b2 (d_in[12]) is constant over the softmax axis -> cancels, unused
    float* out = (float*)d_out;
    const int n = in_sizes[0] / DIM;

    uint8_t* ws = (uint8_t*)d_ws;
    float*    qf   = (float*)ws;                            // n*64 f32
    uint16_t* kvp  = (uint16_t*)(ws + (size_t)n * 256);     // n*128 bf16
    uint16_t* w1p  = (uint16_t*)(ws + (size_t)n * 512);     // 16384 bf16
    uint16_t* w2p  = w1p + 16384;
    uint16_t* pw2p = w2p + 16384;
    const size_t base_bytes = (size_t)n * 512 + 73728;
    uint16_t* relp = (uint16_t*)(ws + base_bytes);

    qkv_kernel<<<(n + 15) / 16, 256, 0, stream>>>(x, wqkv, qf, kvp, n);
    wpack_kernel<<<144, 256, 0, stream>>>(am_w1, am_w2, pm_w2, w1p, w2p, pw2p);

    const size_t avail = (ws_size > base_bytes) ? ws_size - base_bytes : 0;
    const size_t per_pt = (size_t)KNB * 64 * 2;             // 2048 B/point
    int slab_pts = (int)(avail / per_pt);
    if (slab_pts > n) slab_pts = n;
    const int nslabs = (slab_pts > 0) ? (n + slab_pts - 1) / slab_pts : 999;

    if (nslabs <= 4) {
        for (int s = 0; s < nslabs; ++s) {
            const int s0 = s * slab_pts;
            const int s1 = (s0 + slab_pts < n) ? s0 + slab_pts : n;
            const int pairs = (s1 - s0) * KNB;
            posmlp_kernel<<<(pairs + 63) / 64, 256, 0, stream>>>(
                pos, aidx, pm_w1, pm_b1, pm_b2, qf, pw2p, relp, s0, n);
            ptl_main<<<1024, 256, 0, stream>>>(
                aidx, mask, qf, kvp, relp, w1p, w2p, am_b1, out, s0, s1);
        }
    } else {
        ptl_main_fused<<<1024, 256, 0, stream>>>(
            pos, aidx, mask, pm_w1, pm_b1, pm_b2, am_b1,
            qf, kvp, w1p, w2p, pw2p, out, n);
    }
}

// Round 7
// 233.263 us; speedup vs baseline: 1.2481x; 1.2481x over previous
//
#include <hip/hip_runtime.h>
#include <hip/hip_bf16.h>
#include <math.h>
#include <stdint.h>

#define DIM   64
#define KNB   16
#define QKVW  192

typedef short bf16x8 __attribute__((ext_vector_type(8)));
typedef float f32x4  __attribute__((ext_vector_type(4)));

__device__ __forceinline__ short f2bf_s(float x) {
    return (short)__builtin_bit_cast(unsigned short, __float2bfloat16(x));
}
__device__ __forceinline__ float bf2f(uint16_t u) {
    uint32_t v = ((uint32_t)u) << 16;
    return __builtin_bit_cast(float, v);
}

// ---------------------------------------------------------------------------
// qkv -> bf16 [N][192]  (q | k | v)
// ---------------------------------------------------------------------------
__global__ __launch_bounds__(256) void qkv_kernel(
    const float* __restrict__ x, const float* __restrict__ wqkv,
    uint16_t* __restrict__ qkvp, int n)
{
    const int tid = threadIdx.x;
    const int c   = tid & 63;
    const int rq  = tid >> 6;
    const int r0  = blockIdx.x * 16;
    __shared__ float s_x[16][64];
#pragma unroll
    for (int t = 0; t < 4; ++t) {
        const int row = r0 + rq + 4 * t;
        s_x[rq + 4 * t][c] = (row < n) ? x[(size_t)row * 64 + c] : 0.f;
    }
    __syncthreads();
    float aq[4] = {0, 0, 0, 0}, ak[4] = {0, 0, 0, 0}, av[4] = {0, 0, 0, 0};
    for (int d = 0; d < 64; ++d) {
        const float w0 = wqkv[d * QKVW + c];
        const float w1 = wqkv[d * QKVW + 64 + c];
        const float w2 = wqkv[d * QKVW + 128 + c];
#pragma unroll
        for (int t = 0; t < 4; ++t) {
            const float xv = s_x[rq + 4 * t][d];
            aq[t] = fmaf(xv, w0, aq[t]);
            ak[t] = fmaf(xv, w1, ak[t]);
            av[t] = fmaf(xv, w2, av[t]);
        }
    }
#pragma unroll
    for (int t = 0; t < 4; ++t) {
        const int row = r0 + rq + 4 * t;
        if (row < n) {
            qkvp[(size_t)row * QKVW + c]        = (uint16_t)f2bf_s(aq[t]);
            qkvp[(size_t)row * QKVW + 64 + c]   = (uint16_t)f2bf_s(ak[t]);
            qkvp[(size_t)row * QKVW + 128 + c]  = (uint16_t)f2bf_s(av[t]);
        }
    }
}

// ---------------------------------------------------------------------------
// Prepack am_w1 / am_w2 / pm_w2 into bf16 MFMA fragment order.
// Fragment: non-K = lane&15, K = 32*kt + 8*(lane>>4) + j.
// ---------------------------------------------------------------------------
__global__ __launch_bounds__(256) void wpack_kernel(
    const float* __restrict__ am_w1, const float* __restrict__ am_w2,
    const float* __restrict__ pm_w2,
    uint16_t* __restrict__ w1p, uint16_t* __restrict__ w2p, uint16_t* __restrict__ pw2p)
{
    int t = blockIdx.x * 256 + threadIdx.x;
    if (t >= 36864) return;
    int j = t & 7, lane = (t >> 3) & 63, tile = t >> 9;
    int g = lane >> 4, nb = lane & 15;
    if (tile < 32) {
        int mt = tile >> 1, kt = tile & 1;
        w1p[t] = (uint16_t)f2bf_s(am_w1[(32 * kt + 8 * g + j) * 256 + 16 * mt + nb]);
    } else if (tile < 64) {
        int tt = tile - 32;
        int mt = tt >> 3, kt = tt & 7;
        w2p[t - 16384] = (uint16_t)f2bf_s(am_w2[(32 * kt + 8 * g + j) * 64 + 16 * mt + nb]);
    } else {
        int tt = tile - 64;
        int nt = tt >> 1, kt = tt & 1;
        pw2p[t - 32768] = (uint16_t)f2bf_s(pm_w2[(32 * kt + 8 * g + j) * 64 + 16 * nt + nb]);
    }
}

// ---------------------------------------------------------------------------
// Main: 4 points per block-iteration, 4 waves, 2 barriers per 4 points.
//  P1: wave w -> rel of point i0+w (8 MFMA) -> s_rel[w]
//  P2: wave w -> h2[64 pairs][hidden 64w..64w+63] (32 MFMA) -> s_h2 (swizzled);
//      wave pt also writes s_vrel = v + rel for its point
//  P3: wave w -> scores[64 pairs][out 16w..16w+15] (32 MFMA) + softmax + agg
// LDS 52 KB single-buffered -> 3 blocks/CU. No barrier-3 needed: next-iter P1
// writes only s_rel (not read by P3); P2' writes sit behind barrier-1'.
// ---------------------------------------------------------------------------
__global__ __launch_bounds__(256, 2) void ptl_main(
    const float* __restrict__ pos,
    const int* __restrict__ aidx,
    const uint8_t* __restrict__ mask,
    const float* __restrict__ pm_w1,
    const float* __restrict__ pm_b1,
    const float* __restrict__ pm_b2,
    const float* __restrict__ am_b1,
    const uint16_t* __restrict__ qkvp,
    const uint16_t* __restrict__ w1p,
    const uint16_t* __restrict__ w2p,
    const uint16_t* __restrict__ pw2p,
    float* __restrict__ out,
    int npts)
{
    const int tid  = threadIdx.x;
    const int w    = tid >> 6;
    const int lane = tid & 63;
    const int g    = lane >> 4;
    const int nb   = lane & 15;

    __shared__ alignas(16) uint16_t s_rel[4][16][80];   // [pt][nbr][ch], 160B rows
    __shared__ alignas(16) uint16_t s_vrel[64][80];     // [pair][ch]
    __shared__ alignas(16) uint16_t s_h2[64][256];      // [pair][hidden], slot-XOR swz

    // register-resident weights (64 VGPR)
    bf16x8 aw1[4][2], aw2[8];
#pragma unroll
    for (int m = 0; m < 4; ++m)
#pragma unroll
        for (int kt = 0; kt < 2; ++kt)
            aw1[m][kt] = *(const bf16x8*)(w1p + (size_t)(((4 * w + m) * 2 + kt) * 64 + lane) * 8);
#pragma unroll
    for (int kt = 0; kt < 8; ++kt)
        aw2[kt] = *(const bf16x8*)(w2p + (size_t)((w * 8 + kt) * 64 + lane) * 8);

    const int ngroups = (npts + 3) >> 2;
    for (int gb = blockIdx.x; gb < ngroups; gb += gridDim.x) {
        const int i0 = gb * 4;

        // ================= P1: rel for point i0+w =================
        {
            const int ip   = min(i0 + w, npts - 1);
            const int nidx = aidx[ip * KNB + nb];
            const float rx = pos[3 * nidx]     - pos[3 * ip];
            const float ry = pos[3 * nidx + 1] - pos[3 * ip + 1];
            const float rz = pos[3 * nidx + 2] - pos[3 * ip + 2];

            bf16x8 h1f[2];
#pragma unroll
            for (int kt = 0; kt < 2; ++kt) {
                const int hb = 32 * kt + 8 * g;
                float w0[8], w1r[8], w2r[8], bb[8];
                *(float4*)&w0[0]  = *(const float4*)(pm_w1 + hb);
                *(float4*)&w0[4]  = *(const float4*)(pm_w1 + hb + 4);
                *(float4*)&w1r[0] = *(const float4*)(pm_w1 + 64 + hb);
                *(float4*)&w1r[4] = *(const float4*)(pm_w1 + 64 + hb + 4);
                *(float4*)&w2r[0] = *(const float4*)(pm_w1 + 128 + hb);
                *(float4*)&w2r[4] = *(const float4*)(pm_w1 + 128 + hb + 4);
                *(float4*)&bb[0]  = *(const float4*)(pm_b1 + hb);
                *(float4*)&bb[4]  = *(const float4*)(pm_b1 + hb + 4);
                bf16x8 f;
#pragma unroll
                for (int jj = 0; jj < 8; ++jj) {
                    float v = fmaf(rx, w0[jj], fmaf(ry, w1r[jj], fmaf(rz, w2r[jj], bb[jj])));
                    f[jj] = f2bf_s(fmaxf(v, 0.f));
                }
                h1f[kt] = f;
            }
#pragma unroll
            for (int nt = 0; nt < 4; ++nt) {
                const bf16x8 b0 = *(const bf16x8*)(pw2p + (size_t)((nt * 2 + 0) * 64 + lane) * 8);
                const bf16x8 b1 = *(const bf16x8*)(pw2p + (size_t)((nt * 2 + 1) * 64 + lane) * 8);
                f32x4 acc = {0.f, 0.f, 0.f, 0.f};
                acc = __builtin_amdgcn_mfma_f32_16x16x32_bf16(h1f[0], b0, acc, 0, 0, 0);
                acc = __builtin_amdgcn_mfma_f32_16x16x32_bf16(h1f[1], b1, acc, 0, 0, 0);
                const float bias = pm_b2[16 * nt + nb];
#pragma unroll
                for (int r = 0; r < 4; ++r)
                    s_rel[w][4 * g + r][16 * nt + nb] = (uint16_t)f2bf_s(acc[r] + bias);
            }
        }
        __syncthreads();

        // ================= P2: h2 stripe for all 64 pairs =================
#pragma unroll
        for (int pt = 0; pt < 4; ++pt) {
            const int ip   = min(i0 + pt, npts - 1);
            const int nidx = aidx[ip * KNB + nb];
            const uint16_t* kvr = qkvp + (size_t)nidx * QKVW;
            const uint16_t* qr  = qkvp + (size_t)ip * QKVW;

            bf16x8 tf[2];
#pragma unroll
            for (int kt = 0; kt < 2; ++kt) {
                const int cb = 32 * kt + 8 * g;
                const bf16x8 k8 = *(const bf16x8*)(kvr + 64 + cb);
                const bf16x8 q8 = *(const bf16x8*)(qr + cb);
                const bf16x8 r8 = *(const bf16x8*)&s_rel[pt][nb][cb];
                bf16x8 f;
#pragma unroll
                for (int j = 0; j < 8; ++j)
                    f[j] = f2bf_s(bf2f((uint16_t)k8[j]) - bf2f((uint16_t)q8[j]) + bf2f((uint16_t)r8[j]));
                tf[kt] = f;
                if (pt == w) {   // wave-uniform: owning wave writes vrel = v + rel
                    const bf16x8 v8 = *(const bf16x8*)(kvr + 128 + cb);
                    bf16x8 vf;
#pragma unroll
                    for (int j = 0; j < 8; ++j)
                        vf[j] = f2bf_s(bf2f((uint16_t)v8[j]) + bf2f((uint16_t)r8[j]));
                    *(bf16x8*)&s_vrel[16 * pt + nb][cb] = vf;
                }
            }

            f32x4 acc[4];
#pragma unroll
            for (int m = 0; m < 4; ++m) {
                f32x4 a = {0.f, 0.f, 0.f, 0.f};
                a = __builtin_amdgcn_mfma_f32_16x16x32_bf16(aw1[m][0], tf[0], a, 0, 0, 0);
                a = __builtin_amdgcn_mfma_f32_16x16x32_bf16(aw1[m][1], tf[1], a, 0, 0, 0);
                acc[m] = a;
            }
#pragma unroll
            for (int m = 0; m < 4; ++m) {
                const int hb = 16 * (4 * w + m) + 4 * g;
                const float4 b4 = *(const float4*)(am_b1 + hb);
                const uint32_t lo = (uint32_t)(uint16_t)f2bf_s(fmaxf(acc[m][0] + b4.x, 0.f))
                                  | ((uint32_t)(uint16_t)f2bf_s(fmaxf(acc[m][1] + b4.y, 0.f)) << 16);
                const uint32_t hi = (uint32_t)(uint16_t)f2bf_s(fmaxf(acc[m][2] + b4.z, 0.f))
                                  | ((uint32_t)(uint16_t)f2bf_s(fmaxf(acc[m][3] + b4.w, 0.f)) << 16);
                const int sl = (2 * (4 * w + m) + (g >> 1)) ^ (nb & 7);
                *(uint2*)((char*)&s_h2[16 * pt + nb][0] + sl * 16 + 8 * (g & 1)) = make_uint2(lo, hi);
            }
        }
        __syncthreads();

        // ================= P3: scores + softmax + agg, per point mt =========
#pragma unroll
        for (int mt = 0; mt < 4; ++mt) {
            const int ip  = i0 + mt;
            const int ipc = min(ip, npts - 1);

            f32x4 wacc = {0.f, 0.f, 0.f, 0.f};
#pragma unroll
            for (int kt = 0; kt < 8; ++kt) {
                const int sl = (4 * kt + g) ^ (nb & 7);
                const bf16x8 a = *(const bf16x8*)((const char*)&s_h2[16 * mt + nb][0] + sl * 16);
                wacc = __builtin_amdgcn_mfma_f32_16x16x32_bf16(a, aw2[kt], wacc, 0, 0, 0);
            }

            const uchar4 m4 = *(const uchar4*)(mask + (size_t)ipc * KNB + 4 * g);
            const float sc0 = m4.x ? -INFINITY : wacc[0];
            const float sc1 = m4.y ? -INFINITY : wacc[1];
            const float sc2 = m4.z ? -INFINITY : wacc[2];
            const float sc3 = m4.w ? -INFINITY : wacc[3];
            float mx = fmaxf(fmaxf(sc0, sc1), fmaxf(sc2, sc3));
            mx = fmaxf(mx, __shfl_xor(mx, 16));
            mx = fmaxf(mx, __shfl_xor(mx, 32));
            const float e0 = __expf(sc0 - mx), e1 = __expf(sc1 - mx);
            const float e2 = __expf(sc2 - mx), e3 = __expf(sc3 - mx);
            float den = (e0 + e1) + (e2 + e3);

            const int vc = 16 * w + nb;
            const float vr0 = bf2f(s_vrel[16 * mt + 4 * g + 0][vc]);
            const float vr1 = bf2f(s_vrel[16 * mt + 4 * g + 1][vc]);
            const float vr2 = bf2f(s_vrel[16 * mt + 4 * g + 2][vc]);
            const float vr3 = bf2f(s_vrel[16 * mt + 4 * g + 3][vc]);
            float num = e0 * vr0;
            num = fmaf(e1, vr1, num);
            num = fmaf(e2, vr2, num);
            num = fmaf(e3, vr3, num);

            den += __shfl_xor(den, 16); den += __shfl_xor(den, 32);
            num += __shfl_xor(num, 16); num += __shfl_xor(num, 32);
            if (lane < 16 && ip < npts)
                out[(size_t)ip * 64 + vc] = __fdividef(num, den);
        }
        // no third barrier needed (see header comment)
    }
}

// ---------------------------------------------------------------------------
extern "C" void kernel_launch(void* const* d_in, const int* in_sizes, int n_in,
                              void* d_out, int out_size, void* d_ws, size_t ws_size,
                              hipStream_t stream) {
    const float*   x     = (const float*)d_in[0];
    const float*   pos   = (const float*)d_in[1];
    const int*     aidx  = (const int*)d_in[2];
    const uint8_t* mask  = (const uint8_t*)d_in[3];
    const float*   wqkv  = (const float*)d_in[4];
    const float*   pm_w1 = (const float*)d_in[5];
    const float*   pm_b1 = (const float*)d_in[6];
    const float*   pm_w2 = (const float*)d_in[7];
    const float*   pm_b2 = (const float*)d_in[8];
    const float*   am_w1 = (const float*)d_in[9];
    const float*   am_b1 = (const float*)d_in[10];
    const float*   am_w2 = (const float*)d_in[11];
    // am_b2 (d_in[12]) is constant over the softmax axis -> cancels, unused
    float* out = (float*)d_out;
    const int n = in_sizes[0] / DIM;

    uint8_t* ws = (uint8_t*)d_ws;
    uint16_t* qkvp = (uint16_t*)ws;                               // n*192 bf16
    uint16_t* w1p  = (uint16_t*)(ws + (size_t)n * QKVW * 2);      // 16384 bf16
    uint16_t* w2p  = w1p + 16384;                                 // 16384 bf16
    uint16_t* pw2p = w2p + 16384;                                 // 4096 bf16

    qkv_kernel<<<(n + 15) / 16, 256, 0, stream>>>(x, wqkv, qkvp, n);
    wpack_kernel<<<144, 256, 0, stream>>>(am_w1, am_w2, pm_w2, w1p, w2p, pw2p);
    ptl_main<<<1024, 256, 0, stream>>>(pos, aidx, mask, pm_w1, pm_b1, pm_b2, am_b1,
                                       qkvp, w1p, w2p, pw2p, out, n);
}